// Round 5
// baseline (446.566 us; speedup 1.0000x reference)
//
#include <hip/hip_runtime.h>
#include <hip/hip_bf16.h>

// ---------------- types ----------------
using short8 = __attribute__((ext_vector_type(8))) short;   // 8 bf16 (4 VGPRs)
using f32x4  = __attribute__((ext_vector_type(4))) float;   // 4 fp32 acc

#define LSK 72   // LDS row stride (shorts) for Ps tile

#define GLDS(gptr, lptr) __builtin_amdgcn_global_load_lds( \
    (const __attribute__((address_space(1))) void*)(gptr), \
    (__attribute__((address_space(3))) void*)(lptr), 16, 0, 0)

static __device__ __forceinline__ short f2b(float f) {
    unsigned u = __builtin_bit_cast(unsigned, f);
    unsigned r = (u + 0x7fffu + ((u >> 16) & 1u)) >> 16;
    return (short)r;
}

// ---------------- convert kernels ----------------
__global__ void cvt_bf16(const float* __restrict__ in, short* __restrict__ out, int n) {
    int i = (blockIdx.x * 256 + threadIdx.x) * 4;
    if (i >= n) return;
    float4 v = *(const float4*)(in + i);
    short4 o = make_short4(f2b(v.x), f2b(v.y), f2b(v.z), f2b(v.w));
    *(short4*)(out + i) = o;
}

// W f32 [K][N] -> Wt bf16 [N][K]
__global__ void cvt_t_bf16(const float* __restrict__ W, short* __restrict__ Wt, int K, int N) {
    __shared__ short tile[32][33];
    int n0 = blockIdx.x * 32, k0 = blockIdx.y * 32;
    int tx = threadIdx.x, ty = threadIdx.y; // (32,8)
#pragma unroll
    for (int i = 0; i < 4; i++) {
        int r = ty + i * 8;
        tile[r][tx] = f2b(W[(size_t)(k0 + r) * N + n0 + tx]);
    }
    __syncthreads();
#pragma unroll
    for (int i = 0; i < 4; i++) {
        int r = ty + i * 8;
        Wt[(size_t)(n0 + r) * K + k0 + tx] = tile[tx][r];
    }
}

// ---------------- GEMM 128x128x64: C[M][1024] = A[M][1024] @ B, Bt[n][k] ----------------
// mode 0: bf16 [m][n];  mode 1: f32 [m][n]
__global__ __launch_bounds__(256) void gemm128(
    const short* __restrict__ A, const short* __restrict__ Bt,
    const float* __restrict__ bias, void* __restrict__ Cout, int M, int mode)
{
    __shared__ short As[128 * 64];
    __shared__ short Bs[128 * 64];
    const int tid = threadIdx.x;
    const int w = tid >> 6, L = tid & 63, quad = L >> 4, l16 = L & 15;
    const int n0 = blockIdx.x * 128, m0 = blockIdx.y * 128;
    const int K = 1024, N = 1024;
    const int mrow0 = (w >> 1) * 64, ncol0 = (w & 1) * 64;

    const int srow_in = L >> 3;                        // 0..7 within chunk
    const int sgcol   = ((L & 7) ^ (srow_in & 7)) * 8; // swizzled global col (shorts)

    f32x4 acc[4][4];
#pragma unroll
    for (int mi = 0; mi < 4; mi++)
#pragma unroll
        for (int ni = 0; ni < 4; ni++) acc[mi][ni] = (f32x4){0.f, 0.f, 0.f, 0.f};

    for (int k0 = 0; k0 < K; k0 += 64) {
#pragma unroll
        for (int j = 0; j < 4; j++) {
            int c = w * 4 + j;
            int row = c * 8 + srow_in;
            const short* ga = A  + (size_t)(m0 + row) * K + k0 + sgcol;
            const short* gb = Bt + (size_t)(n0 + row) * K + k0 + sgcol;
            GLDS(ga, &As[c * 512]);
            GLDS(gb, &Bs[c * 512]);
        }
        __syncthreads();
#pragma unroll
        for (int kk = 0; kk < 64; kk += 32) {
            int swz = (((kk >> 3) + quad) ^ (l16 & 7)) << 3;
            short8 af[4], bf[4];
#pragma unroll
            for (int mi = 0; mi < 4; mi++)
                af[mi] = *(const short8*)&As[(mrow0 + mi * 16 + l16) * 64 + swz];
#pragma unroll
            for (int ni = 0; ni < 4; ni++)
                bf[ni] = *(const short8*)&Bs[(ncol0 + ni * 16 + l16) * 64 + swz];
#pragma unroll
            for (int mi = 0; mi < 4; mi++)
#pragma unroll
                for (int ni = 0; ni < 4; ni++)
                    acc[mi][ni] = __builtin_amdgcn_mfma_f32_16x16x32_bf16(af[mi], bf[ni], acc[mi][ni], 0, 0, 0);
        }
        __syncthreads();
    }
#pragma unroll
    for (int ni = 0; ni < 4; ni++) {
        int n = n0 + ncol0 + ni * 16 + l16;
        float bv = bias ? bias[n] : 0.f;
#pragma unroll
        for (int mi = 0; mi < 4; mi++) {
#pragma unroll
            for (int r = 0; r < 4; r++) {
                int m = m0 + mrow0 + mi * 16 + quad * 4 + r;
                float v = acc[mi][ni][r] + bv;
                if (mode == 1) ((float*)Cout)[(size_t)m * N + n] = v;
                else           ((short*)Cout)[(size_t)m * N + n] = f2b(v);
            }
        }
    }
}

// ---------------- fused K+V projection: shares the A (hiddens) tile ----------------
// Kout: bf16 [m][n];  Vtout: bf16 [b][h][d][s]
__global__ __launch_bounds__(256) void gemm_kv(
    const short* __restrict__ A, const short* __restrict__ Btk, const short* __restrict__ Btv,
    short* __restrict__ Kout, short* __restrict__ Vtout)
{
    __shared__ short As[128 * 64];
    __shared__ short Bks[128 * 64];
    __shared__ short Bvs[128 * 64];
    const int tid = threadIdx.x;
    const int w = tid >> 6, L = tid & 63, quad = L >> 4, l16 = L & 15;
    const int n0 = blockIdx.x * 128, m0 = blockIdx.y * 128;
    const int K = 1024, N = 1024;
    const int mrow0 = (w >> 1) * 64, ncol0 = (w & 1) * 64;

    const int srow_in = L >> 3;
    const int sgcol   = ((L & 7) ^ (srow_in & 7)) * 8;

    f32x4 acc[2][4][4];
#pragma unroll
    for (int o = 0; o < 2; o++)
#pragma unroll
        for (int mi = 0; mi < 4; mi++)
#pragma unroll
            for (int ni = 0; ni < 4; ni++) acc[o][mi][ni] = (f32x4){0.f, 0.f, 0.f, 0.f};

    for (int k0 = 0; k0 < K; k0 += 64) {
#pragma unroll
        for (int j = 0; j < 4; j++) {
            int c = w * 4 + j;
            int row = c * 8 + srow_in;
            GLDS(A   + (size_t)(m0 + row) * K + k0 + sgcol, &As[c * 512]);
            GLDS(Btk + (size_t)(n0 + row) * K + k0 + sgcol, &Bks[c * 512]);
            GLDS(Btv + (size_t)(n0 + row) * K + k0 + sgcol, &Bvs[c * 512]);
        }
        __syncthreads();
#pragma unroll
        for (int kk = 0; kk < 64; kk += 32) {
            int swz = (((kk >> 3) + quad) ^ (l16 & 7)) << 3;
            short8 af[4];
#pragma unroll
            for (int mi = 0; mi < 4; mi++)
                af[mi] = *(const short8*)&As[(mrow0 + mi * 16 + l16) * 64 + swz];
            {   // K-output MFMAs
                short8 bf[4];
#pragma unroll
                for (int ni = 0; ni < 4; ni++)
                    bf[ni] = *(const short8*)&Bks[(ncol0 + ni * 16 + l16) * 64 + swz];
#pragma unroll
                for (int mi = 0; mi < 4; mi++)
#pragma unroll
                    for (int ni = 0; ni < 4; ni++)
                        acc[0][mi][ni] = __builtin_amdgcn_mfma_f32_16x16x32_bf16(af[mi], bf[ni], acc[0][mi][ni], 0, 0, 0);
            }
            {   // V-output MFMAs
                short8 bf[4];
#pragma unroll
                for (int ni = 0; ni < 4; ni++)
                    bf[ni] = *(const short8*)&Bvs[(ncol0 + ni * 16 + l16) * 64 + swz];
#pragma unroll
                for (int mi = 0; mi < 4; mi++)
#pragma unroll
                    for (int ni = 0; ni < 4; ni++)
                        acc[1][mi][ni] = __builtin_amdgcn_mfma_f32_16x16x32_bf16(af[mi], bf[ni], acc[1][mi][ni], 0, 0, 0);
            }
        }
        __syncthreads();
    }
#pragma unroll
    for (int ni = 0; ni < 4; ni++) {
        int n = n0 + ncol0 + ni * 16 + l16;
        int h = n >> 6, d = n & 63;
#pragma unroll
        for (int mi = 0; mi < 4; mi++) {
#pragma unroll
            for (int r = 0; r < 4; r++) {
                int m = m0 + mrow0 + mi * 16 + quad * 4 + r;
                Kout[(size_t)m * N + n] = f2b(acc[0][mi][ni][r]);
                int b = m >> 11, s = m & 2047;
                Vtout[(((size_t)b * 16 + h) * 64 + d) * 2048 + s] = f2b(acc[1][mi][ni][r]);
            }
        }
    }
}

// ---------------- flash attention: t-tile=128, s-tile=128, glds swizzled staging ----------------
__global__ __launch_bounds__(512) void attn_flash(
    const short* __restrict__ Qb, const short* __restrict__ Kb, const short* __restrict__ Vtb,
    const int* __restrict__ mask, short* __restrict__ Cb, float* __restrict__ lse)
{
    __shared__ short Qs[128 * 64];
    __shared__ short Ks[128 * 64];      // K rows s0..s0+127
    __shared__ short Vts[128 * 64];     // two [64 d][64 s] halves
    __shared__ short Ps[128 * LSK];
    __shared__ float neg[128];
    const int tid = threadIdx.x;
    const int w = tid >> 6, L = tid & 63, quad = L >> 4, l16 = L & 15;
    const int t0 = blockIdx.x * 128, h = blockIdx.y, b = blockIdx.z;
    const int S = 2048, T = 512, H = 1024;
    const int trow = w * 16;
    const int srow = L >> 3;
    const int sg   = ((L & 7) ^ srow) * 8;

    // stage Q tile [128][64] via glds (2 chunks per wave)
#pragma unroll
    for (int j = 0; j < 2; j++) {
        int row = w * 16 + j * 8 + srow;
        GLDS(Qb + ((size_t)b * T + t0 + row) * H + h * 64 + sg, &Qs[(w * 16 + j * 8) * 64]);
    }
    __syncthreads();
    short8 aq[2];
#pragma unroll
    for (int kk = 0; kk < 2; kk++)
        aq[kk] = *(const short8*)&Qs[(trow + l16) * 64 + ((kk * 4 + quad) ^ (l16 & 7)) * 8];

    f32x4 Oacc[4];
#pragma unroll
    for (int nt = 0; nt < 4; nt++) Oacc[nt] = (f32x4){0.f, 0.f, 0.f, 0.f};
    float lsum[4] = {0.f, 0.f, 0.f, 0.f};

    for (int s0 = 0; s0 < S; s0 += 128) {
        // stage K [128][64] (16 chunks) + Vt 2x[64][64] (16 chunks): 2+2 per wave
#pragma unroll
        for (int j = 0; j < 2; j++) {
            int krow = w * 16 + j * 8 + srow;
            GLDS(Kb + ((size_t)b * S + s0 + krow) * H + h * 64 + sg, &Ks[(w * 16 + j * 8) * 64]);
            int c = w * 2 + j, hf = c >> 3, d0 = (c & 7) * 8;
            GLDS(Vtb + (((size_t)b * 16 + h) * 64 + d0 + srow) * S + s0 + hf * 64 + sg, &Vts[c * 512]);
        }
        if (tid < 128) neg[tid] = mask[(size_t)b * S + s0 + tid] ? 0.f : -1e20f;
        __syncthreads();
#pragma unroll
        for (int hf = 0; hf < 2; hf++) {
            // S = Q K^T for this 64-s half
            f32x4 sacc[4];
#pragma unroll
            for (int nt = 0; nt < 4; nt++) sacc[nt] = (f32x4){0.f, 0.f, 0.f, 0.f};
#pragma unroll
            for (int kk = 0; kk < 2; kk++) {
#pragma unroll
                for (int nt = 0; nt < 4; nt++) {
                    short8 bf = *(const short8*)&Ks[(hf * 64 + nt * 16 + l16) * 64 + ((kk * 4 + quad) ^ (l16 & 7)) * 8];
                    sacc[nt] = __builtin_amdgcn_mfma_f32_16x16x32_bf16(aq[kk], bf, sacc[nt], 0, 0, 0);
                }
            }
            // p = exp(s/8 + neg); write Ps (wave-private rows)
#pragma unroll
            for (int nt = 0; nt < 4; nt++) {
                float ng = neg[hf * 64 + nt * 16 + l16];
#pragma unroll
                for (int r = 0; r < 4; r++) {
                    float e = __expf(fmaf(sacc[nt][r], 0.125f, ng));
                    lsum[r] += e;
                    Ps[(trow + quad * 4 + r) * LSK + nt * 16 + l16] = f2b(e);
                }
            }
            // O += P V
#pragma unroll
            for (int kk = 0; kk < 2; kk++) {
                short8 af = *(const short8*)&Ps[(trow + l16) * LSK + kk * 32 + quad * 8];
#pragma unroll
                for (int nt = 0; nt < 4; nt++) {
                    short8 bf = *(const short8*)&Vts[hf * 4096 + (nt * 16 + l16) * 64 + ((kk * 4 + quad) ^ (l16 & 7)) * 8];
                    Oacc[nt] = __builtin_amdgcn_mfma_f32_16x16x32_bf16(af, bf, Oacc[nt], 0, 0, 0);
                }
            }
        }
        __syncthreads();
    }
    // rowsum reduce across the 16 lanes of each quad-group
#pragma unroll
    for (int r = 0; r < 4; r++) {
#pragma unroll
        for (int off = 1; off < 16; off <<= 1)
            lsum[r] += __shfl_xor(lsum[r], off, 64);
    }
#pragma unroll
    for (int r = 0; r < 4; r++) {
        float inv = 1.0f / lsum[r];
        int t = t0 + trow + quad * 4 + r;
#pragma unroll
        for (int nt = 0; nt < 4; nt++) {
            int d = nt * 16 + l16;
            Cb[((size_t)b * T + t) * H + h * 64 + d] = f2b(Oacc[nt][r] * inv);
        }
        if (l16 == 0)
            lse[((size_t)b * 16 + h) * T + t] = __logf(lsum[r]);
    }
}

// ---------------- a_mean: out[b][t][s] = mean_h exp(qk/8 + neg - lse_h) ----------------
__global__ __launch_bounds__(256) void attn_amean(
    const short* __restrict__ Qb, const short* __restrict__ Kb,
    const int* __restrict__ mask, const float* __restrict__ lse, float* __restrict__ outA)
{
    __shared__ short Qs[64 * 64];
    __shared__ short Ks[64 * 64];
    __shared__ float neg[64];
    __shared__ float lss[16 * 64];
    const int tid = threadIdx.x;
    const int w = tid >> 6, L = tid & 63, quad = L >> 4, l16 = L & 15;
    const int s0 = blockIdx.x * 64, t0 = blockIdx.y * 64, b = blockIdx.z;
    const int S = 2048, T = 512, H = 1024;
    const int srow = L >> 3;
    const int sg   = ((L & 7) ^ srow) * 8;

    if (tid < 64) neg[tid] = mask[(size_t)b * S + s0 + tid] ? 0.f : -1e20f;
    for (int i = tid; i < 16 * 64; i += 256) {
        int hh = i >> 6, tt = i & 63;
        lss[i] = lse[((size_t)b * 16 + hh) * T + t0 + tt];
    }
    float am[4][4] = {};
    for (int h = 0; h < 16; h++) {
        __syncthreads();  // protects neg/lss on first iter, prior-head reads after
#pragma unroll
        for (int j = 0; j < 2; j++) {
            int row = w * 16 + j * 8 + srow;
            GLDS(Qb + ((size_t)b * T + t0 + row) * H + h * 64 + sg, &Qs[(w * 16 + j * 8) * 64]);
            GLDS(Kb + ((size_t)b * S + s0 + row) * H + h * 64 + sg, &Ks[(w * 16 + j * 8) * 64]);
        }
        __syncthreads();
        short8 aq[2];
#pragma unroll
        for (int kk = 0; kk < 2; kk++)
            aq[kk] = *(const short8*)&Qs[(w * 16 + l16) * 64 + ((kk * 4 + quad) ^ (l16 & 7)) * 8];
        f32x4 sacc[4];
#pragma unroll
        for (int nt = 0; nt < 4; nt++) sacc[nt] = (f32x4){0.f, 0.f, 0.f, 0.f};
#pragma unroll
        for (int kk = 0; kk < 2; kk++) {
#pragma unroll
            for (int nt = 0; nt < 4; nt++) {
                short8 bf = *(const short8*)&Ks[(nt * 16 + l16) * 64 + ((kk * 4 + quad) ^ (l16 & 7)) * 8];
                sacc[nt] = __builtin_amdgcn_mfma_f32_16x16x32_bf16(aq[kk], bf, sacc[nt], 0, 0, 0);
            }
        }
#pragma unroll
        for (int nt = 0; nt < 4; nt++) {
            float ng = neg[nt * 16 + l16];
#pragma unroll
            for (int r = 0; r < 4; r++) {
                int trow = w * 16 + quad * 4 + r;
                am[nt][r] += __expf(fmaf(sacc[nt][r], 0.125f, ng - lss[h * 64 + trow]));
            }
        }
    }
#pragma unroll
    for (int r = 0; r < 4; r++) {
        int t = t0 + w * 16 + quad * 4 + r;
#pragma unroll
        for (int nt = 0; nt < 4; nt++) {
            int s = s0 + nt * 16 + l16;
            outA[((size_t)b * T + t) * S + s] = am[nt][r] * 0.0625f;
        }
    }
}

// ---------------- launch ----------------
extern "C" void kernel_launch(void* const* d_in, const int* in_sizes, int n_in,
                              void* d_out, int out_size, void* d_ws, size_t ws_size,
                              hipStream_t stream) {
    const float* hiddens = (const float*)d_in[0];
    const float* query   = (const float*)d_in[1];
    const int*   mask    = (const int*)d_in[2];
    const float* W_q = (const float*)d_in[3];
    const float* b_q = (const float*)d_in[4];
    const float* W_k = (const float*)d_in[5];
    const float* W_v = (const float*)d_in[6];
    const float* W_o = (const float*)d_in[7];
    const float* b_o = (const float*)d_in[8];
    float* out = (float*)d_out;

    constexpr size_t N_H  = 8UL * 2048 * 1024;  // 16777216
    constexpr size_t N_QH = 8UL * 512 * 1024;   // 4194304
    constexpr size_t N_W  = 1024UL * 1024;      // 1048576
    char* ws = (char*)d_ws;
    short* Hb   = (short*)(ws);
    short* QHb  = (short*)(ws + N_H * 2);
    short* Wqt  = (short*)(ws + N_H * 2 + N_QH * 2);
    short* Wkt  = Wqt + N_W;
    short* Wvt  = Wkt + N_W;
    short* Wot  = Wvt + N_W;
    short* Qb   = Wot + N_W;
    short* Kb   = Qb + N_QH;
    short* Vtb  = Kb + N_H;   // V stored transposed: [b][h][d][s]
    short* Cb   = Vtb + N_H;
    float* lseP = (float*)(Cb + N_QH);

    cvt_bf16<<<16384, 256, 0, stream>>>(hiddens, Hb, (int)N_H);
    cvt_bf16<<<4096, 256, 0, stream>>>(query, QHb, (int)N_QH);
    dim3 tgrid(32, 32), tblk(32, 8);
    cvt_t_bf16<<<tgrid, tblk, 0, stream>>>(W_q, Wqt, 1024, 1024);
    cvt_t_bf16<<<tgrid, tblk, 0, stream>>>(W_k, Wkt, 1024, 1024);
    cvt_t_bf16<<<tgrid, tblk, 0, stream>>>(W_v, Wvt, 1024, 1024);
    cvt_t_bf16<<<tgrid, tblk, 0, stream>>>(W_o, Wot, 1024, 1024);

    gemm128<<<dim3(8, 32), 256, 0, stream>>>(QHb, Wqt, b_q, Qb, 4096, 0);
    gemm_kv<<<dim3(8, 128), 256, 0, stream>>>(Hb, Wkt, Wvt, Kb, Vtb);

    attn_flash<<<dim3(4, 16, 8), 512, 0, stream>>>(Qb, Kb, Vtb, mask, Cb, lseP);

    gemm128<<<dim3(8, 32), 256, 0, stream>>>(Cb, Wot, b_o, out, 4096, 1);
    attn_amean<<<dim3(32, 8, 8), 256, 0, stream>>>(Qb, Kb, mask, lseP, out + N_QH);
}

// Round 6
// 433.849 us; speedup vs baseline: 1.0293x; 1.0293x over previous
//
#include <hip/hip_runtime.h>
#include <hip/hip_bf16.h>

// ---------------- types ----------------
using short8 = __attribute__((ext_vector_type(8))) short;   // 8 bf16 (4 VGPRs)
using f32x4  = __attribute__((ext_vector_type(4))) float;   // 4 fp32 acc

#define LSK 72   // LDS row stride (shorts) for Ps tile

#define GLDS(gptr, lptr) __builtin_amdgcn_global_load_lds( \
    (const __attribute__((address_space(1))) void*)(gptr), \
    (__attribute__((address_space(3))) void*)(lptr), 16, 0, 0)

static __device__ __forceinline__ short f2b(float f) {
    unsigned u = __builtin_bit_cast(unsigned, f);
    unsigned r = (u + 0x7fffu + ((u >> 16) & 1u)) >> 16;
    return (short)r;
}

// ---------------- convert kernels ----------------
__global__ void cvt_bf16(const float* __restrict__ in, short* __restrict__ out, int n) {
    int i = (blockIdx.x * 256 + threadIdx.x) * 4;
    if (i >= n) return;
    float4 v = *(const float4*)(in + i);
    short4 o = make_short4(f2b(v.x), f2b(v.y), f2b(v.z), f2b(v.w));
    *(short4*)(out + i) = o;
}

// W f32 [K][N] -> Wt bf16 [N][K]
__global__ void cvt_t_bf16(const float* __restrict__ W, short* __restrict__ Wt, int K, int N) {
    __shared__ short tile[32][33];
    int n0 = blockIdx.x * 32, k0 = blockIdx.y * 32;
    int tx = threadIdx.x, ty = threadIdx.y; // (32,8)
#pragma unroll
    for (int i = 0; i < 4; i++) {
        int r = ty + i * 8;
        tile[r][tx] = f2b(W[(size_t)(k0 + r) * N + n0 + tx]);
    }
    __syncthreads();
#pragma unroll
    for (int i = 0; i < 4; i++) {
        int r = ty + i * 8;
        Wt[(size_t)(n0 + r) * K + k0 + tx] = tile[tx][r];
    }
}

// ---------------- GEMM 128x128x64: C[M][1024] = A[M][1024] @ B, Bt[n][k] ----------------
// mode 0: bf16 [m][n] (N=1024);  mode 1: f32 [m][n] (N=1024)
// mode 2: dual KV (grid.x=16, n<1024 -> Cout=K bf16 [m][1024]; n>=1024 -> Cout2=Vt [b][h][d][s])
// XCD-aware swizzle: lin%8 selects XCD-band of m-rows; consecutive slots share A-tile in L2.
__global__ __launch_bounds__(256) void gemm128(
    const short* __restrict__ A, const short* __restrict__ Bt,
    const float* __restrict__ bias, void* __restrict__ Cout, void* __restrict__ Cout2,
    int M, int mode)
{
    __shared__ short As[128 * 64];
    __shared__ short Bs[128 * 64];
    const int tid = threadIdx.x;
    const int w = tid >> 6, L = tid & 63, quad = L >> 4, l16 = L & 15;

    // XCD swizzle (gridDim.y % 8 == 0)
    const int lin = blockIdx.y * gridDim.x + blockIdx.x;
    const int xcd = lin & 7, idx = lin >> 3;
    const int mPer = gridDim.y >> 3;
    const int my = xcd * mPer + idx / gridDim.x;
    const int nx = idx % gridDim.x;
    const int n0 = nx * 128, m0 = my * 128;

    const int K = 1024;
    const int mrow0 = (w >> 1) * 64, ncol0 = (w & 1) * 64;

    const int srow_in = L >> 3;                        // 0..7 within chunk
    const int sgcol   = ((L & 7) ^ (srow_in & 7)) * 8; // swizzled global col (shorts)

    f32x4 acc[4][4];
#pragma unroll
    for (int mi = 0; mi < 4; mi++)
#pragma unroll
        for (int ni = 0; ni < 4; ni++) acc[mi][ni] = (f32x4){0.f, 0.f, 0.f, 0.f};

    for (int k0 = 0; k0 < K; k0 += 64) {
#pragma unroll
        for (int j = 0; j < 4; j++) {
            int c = w * 4 + j;
            int row = c * 8 + srow_in;
            const short* ga = A  + (size_t)(m0 + row) * K + k0 + sgcol;
            const short* gb = Bt + (size_t)(n0 + row) * K + k0 + sgcol;
            GLDS(ga, &As[c * 512]);
            GLDS(gb, &Bs[c * 512]);
        }
        __syncthreads();
#pragma unroll
        for (int kk = 0; kk < 64; kk += 32) {
            int swz = (((kk >> 3) + quad) ^ (l16 & 7)) << 3;
            short8 af[4], bf[4];
#pragma unroll
            for (int mi = 0; mi < 4; mi++)
                af[mi] = *(const short8*)&As[(mrow0 + mi * 16 + l16) * 64 + swz];
#pragma unroll
            for (int ni = 0; ni < 4; ni++)
                bf[ni] = *(const short8*)&Bs[(ncol0 + ni * 16 + l16) * 64 + swz];
#pragma unroll
            for (int mi = 0; mi < 4; mi++)
#pragma unroll
                for (int ni = 0; ni < 4; ni++)
                    acc[mi][ni] = __builtin_amdgcn_mfma_f32_16x16x32_bf16(af[mi], bf[ni], acc[mi][ni], 0, 0, 0);
        }
        __syncthreads();
    }
#pragma unroll
    for (int ni = 0; ni < 4; ni++) {
        int n = n0 + ncol0 + ni * 16 + l16;
        float bv = (mode != 2 && bias) ? bias[n] : 0.f;
#pragma unroll
        for (int mi = 0; mi < 4; mi++) {
#pragma unroll
            for (int r = 0; r < 4; r++) {
                int m = m0 + mrow0 + mi * 16 + quad * 4 + r;
                float v = acc[mi][ni][r] + bv;
                if (mode == 1)      ((float*)Cout)[(size_t)m * 1024 + n] = v;
                else if (mode == 0) ((short*)Cout)[(size_t)m * 1024 + n] = f2b(v);
                else {
                    if (n < 1024) ((short*)Cout)[(size_t)m * 1024 + n] = f2b(v);
                    else {
                        int h = (n - 1024) >> 6, d = n & 63;
                        int b = m >> 11, s = m & 2047;
                        ((short*)Cout2)[(((size_t)b * 16 + h) * 64 + d) * 2048 + s] = f2b(v);
                    }
                }
            }
        }
    }
}

// ---------------- flash attention: t-tile=128, s-tile=128, glds swizzled staging ----------------
__global__ __launch_bounds__(512) void attn_flash(
    const short* __restrict__ Qb, const short* __restrict__ Kb, const short* __restrict__ Vtb,
    const int* __restrict__ mask, short* __restrict__ Cb, float* __restrict__ lse)
{
    __shared__ short Qs[128 * 64];
    __shared__ short Ks[128 * 64];      // K rows s0..s0+127
    __shared__ short Vts[128 * 64];     // two [64 d][64 s] halves
    __shared__ short Ps[128 * LSK];
    __shared__ float neg[128];
    const int tid = threadIdx.x;
    const int w = tid >> 6, L = tid & 63, quad = L >> 4, l16 = L & 15;
    const int t0 = blockIdx.x * 128, h = blockIdx.y, b = blockIdx.z;
    const int S = 2048, T = 512, H = 1024;
    const int trow = w * 16;
    const int srow = L >> 3;
    const int sg   = ((L & 7) ^ srow) * 8;

    // stage Q tile [128][64] via glds (2 chunks per wave)
#pragma unroll
    for (int j = 0; j < 2; j++) {
        int row = w * 16 + j * 8 + srow;
        GLDS(Qb + ((size_t)b * T + t0 + row) * H + h * 64 + sg, &Qs[(w * 16 + j * 8) * 64]);
    }
    __syncthreads();
    short8 aq[2];
#pragma unroll
    for (int kk = 0; kk < 2; kk++)
        aq[kk] = *(const short8*)&Qs[(trow + l16) * 64 + ((kk * 4 + quad) ^ (l16 & 7)) * 8];

    f32x4 Oacc[4];
#pragma unroll
    for (int nt = 0; nt < 4; nt++) Oacc[nt] = (f32x4){0.f, 0.f, 0.f, 0.f};
    float lsum[4] = {0.f, 0.f, 0.f, 0.f};

    for (int s0 = 0; s0 < S; s0 += 128) {
        // stage K [128][64] (16 chunks) + Vt 2x[64][64] (16 chunks): 2+2 per wave
#pragma unroll
        for (int j = 0; j < 2; j++) {
            int krow = w * 16 + j * 8 + srow;
            GLDS(Kb + ((size_t)b * S + s0 + krow) * H + h * 64 + sg, &Ks[(w * 16 + j * 8) * 64]);
            int c = w * 2 + j, hf = c >> 3, d0 = (c & 7) * 8;
            GLDS(Vtb + (((size_t)b * 16 + h) * 64 + d0 + srow) * S + s0 + hf * 64 + sg, &Vts[c * 512]);
        }
        if (tid < 128) neg[tid] = mask[(size_t)b * S + s0 + tid] ? 0.f : -1e20f;
        __syncthreads();
#pragma unroll
        for (int hf = 0; hf < 2; hf++) {
            // S = Q K^T for this 64-s half
            f32x4 sacc[4];
#pragma unroll
            for (int nt = 0; nt < 4; nt++) sacc[nt] = (f32x4){0.f, 0.f, 0.f, 0.f};
#pragma unroll
            for (int kk = 0; kk < 2; kk++) {
#pragma unroll
                for (int nt = 0; nt < 4; nt++) {
                    short8 bf = *(const short8*)&Ks[(hf * 64 + nt * 16 + l16) * 64 + ((kk * 4 + quad) ^ (l16 & 7)) * 8];
                    sacc[nt] = __builtin_amdgcn_mfma_f32_16x16x32_bf16(aq[kk], bf, sacc[nt], 0, 0, 0);
                }
            }
            // p = exp(s/8 + neg); write Ps (wave-private rows)
#pragma unroll
            for (int nt = 0; nt < 4; nt++) {
                float ng = neg[hf * 64 + nt * 16 + l16];
#pragma unroll
                for (int r = 0; r < 4; r++) {
                    float e = __expf(fmaf(sacc[nt][r], 0.125f, ng));
                    lsum[r] += e;
                    Ps[(trow + quad * 4 + r) * LSK + nt * 16 + l16] = f2b(e);
                }
            }
            // O += P V
#pragma unroll
            for (int kk = 0; kk < 2; kk++) {
                short8 af = *(const short8*)&Ps[(trow + l16) * LSK + kk * 32 + quad * 8];
#pragma unroll
                for (int nt = 0; nt < 4; nt++) {
                    short8 bf = *(const short8*)&Vts[hf * 4096 + (nt * 16 + l16) * 64 + ((kk * 4 + quad) ^ (l16 & 7)) * 8];
                    Oacc[nt] = __builtin_amdgcn_mfma_f32_16x16x32_bf16(af, bf, Oacc[nt], 0, 0, 0);
                }
            }
        }
        __syncthreads();
    }
    // rowsum reduce across the 16 lanes of each quad-group
#pragma unroll
    for (int r = 0; r < 4; r++) {
#pragma unroll
        for (int off = 1; off < 16; off <<= 1)
            lsum[r] += __shfl_xor(lsum[r], off, 64);
    }
#pragma unroll
    for (int r = 0; r < 4; r++) {
        float inv = 1.0f / lsum[r];
        int t = t0 + trow + quad * 4 + r;
#pragma unroll
        for (int nt = 0; nt < 4; nt++) {
            int d = nt * 16 + l16;
            Cb[((size_t)b * T + t) * H + h * 64 + d] = f2b(Oacc[nt][r] * inv);
        }
        if (l16 == 0)
            lse[((size_t)b * 16 + h) * T + t] = __logf(lsum[r]);
    }
}

// ---------------- a_mean: out[b][t][s] = mean_h exp(qk/8 + neg - lse_h) ----------------
__global__ __launch_bounds__(256) void attn_amean(
    const short* __restrict__ Qb, const short* __restrict__ Kb,
    const int* __restrict__ mask, const float* __restrict__ lse, float* __restrict__ outA)
{
    __shared__ short Qs[64 * 64];
    __shared__ short Ks[64 * 64];
    __shared__ float neg[64];
    __shared__ float lss[16 * 64];
    const int tid = threadIdx.x;
    const int w = tid >> 6, L = tid & 63, quad = L >> 4, l16 = L & 15;
    const int s0 = blockIdx.x * 64, t0 = blockIdx.y * 64, b = blockIdx.z;
    const int S = 2048, T = 512, H = 1024;
    const int srow = L >> 3;
    const int sg   = ((L & 7) ^ srow) * 8;

    if (tid < 64) neg[tid] = mask[(size_t)b * S + s0 + tid] ? 0.f : -1e20f;
    for (int i = tid; i < 16 * 64; i += 256) {
        int hh = i >> 6, tt = i & 63;
        lss[i] = lse[((size_t)b * 16 + hh) * T + t0 + tt];
    }
    float am[4][4] = {};
    for (int h = 0; h < 16; h++) {
        __syncthreads();  // protects neg/lss on first iter, prior-head reads after
#pragma unroll
        for (int j = 0; j < 2; j++) {
            int row = w * 16 + j * 8 + srow;
            GLDS(Qb + ((size_t)b * T + t0 + row) * H + h * 64 + sg, &Qs[(w * 16 + j * 8) * 64]);
            GLDS(Kb + ((size_t)b * S + s0 + row) * H + h * 64 + sg, &Ks[(w * 16 + j * 8) * 64]);
        }
        __syncthreads();
        short8 aq[2];
#pragma unroll
        for (int kk = 0; kk < 2; kk++)
            aq[kk] = *(const short8*)&Qs[(w * 16 + l16) * 64 + ((kk * 4 + quad) ^ (l16 & 7)) * 8];
        f32x4 sacc[4];
#pragma unroll
        for (int nt = 0; nt < 4; nt++) sacc[nt] = (f32x4){0.f, 0.f, 0.f, 0.f};
#pragma unroll
        for (int kk = 0; kk < 2; kk++) {
#pragma unroll
            for (int nt = 0; nt < 4; nt++) {
                short8 bf = *(const short8*)&Ks[(nt * 16 + l16) * 64 + ((kk * 4 + quad) ^ (l16 & 7)) * 8];
                sacc[nt] = __builtin_amdgcn_mfma_f32_16x16x32_bf16(aq[kk], bf, sacc[nt], 0, 0, 0);
            }
        }
#pragma unroll
        for (int nt = 0; nt < 4; nt++) {
            float ng = neg[nt * 16 + l16];
#pragma unroll
            for (int r = 0; r < 4; r++) {
                int trow = w * 16 + quad * 4 + r;
                am[nt][r] += __expf(fmaf(sacc[nt][r], 0.125f, ng - lss[h * 64 + trow]));
            }
        }
    }
#pragma unroll
    for (int r = 0; r < 4; r++) {
        int t = t0 + w * 16 + quad * 4 + r;
#pragma unroll
        for (int nt = 0; nt < 4; nt++) {
            int s = s0 + nt * 16 + l16;
            outA[((size_t)b * T + t) * S + s] = am[nt][r] * 0.0625f;
        }
    }
}

// ---------------- launch ----------------
extern "C" void kernel_launch(void* const* d_in, const int* in_sizes, int n_in,
                              void* d_out, int out_size, void* d_ws, size_t ws_size,
                              hipStream_t stream) {
    const float* hiddens = (const float*)d_in[0];
    const float* query   = (const float*)d_in[1];
    const int*   mask    = (const int*)d_in[2];
    const float* W_q = (const float*)d_in[3];
    const float* b_q = (const float*)d_in[4];
    const float* W_k = (const float*)d_in[5];
    const float* W_v = (const float*)d_in[6];
    const float* W_o = (const float*)d_in[7];
    const float* b_o = (const float*)d_in[8];
    float* out = (float*)d_out;

    constexpr size_t N_H  = 8UL * 2048 * 1024;  // 16777216
    constexpr size_t N_QH = 8UL * 512 * 1024;   // 4194304
    constexpr size_t N_W  = 1024UL * 1024;      // 1048576
    char* ws = (char*)d_ws;
    short* Hb   = (short*)(ws);
    short* QHb  = (short*)(ws + N_H * 2);
    short* Wqt  = (short*)(ws + N_H * 2 + N_QH * 2);
    short* Wkt  = Wqt + N_W;
    short* Wvt  = Wkt + N_W;   // contiguous after Wkt: enables N=2048 dual GEMM
    short* Wot  = Wvt + N_W;
    short* Qb   = Wot + N_W;
    short* Kb   = Qb + N_QH;
    short* Vtb  = Kb + N_H;    // V stored transposed: [b][h][d][s]
    short* Cb   = Vtb + N_H;
    float* lseP = (float*)(Cb + N_QH);

    cvt_bf16<<<16384, 256, 0, stream>>>(hiddens, Hb, (int)N_H);
    cvt_bf16<<<4096, 256, 0, stream>>>(query, QHb, (int)N_QH);
    dim3 tgrid(32, 32), tblk(32, 8);
    cvt_t_bf16<<<tgrid, tblk, 0, stream>>>(W_q, Wqt, 1024, 1024);
    cvt_t_bf16<<<tgrid, tblk, 0, stream>>>(W_k, Wkt, 1024, 1024);
    cvt_t_bf16<<<tgrid, tblk, 0, stream>>>(W_v, Wvt, 1024, 1024);
    cvt_t_bf16<<<tgrid, tblk, 0, stream>>>(W_o, Wot, 1024, 1024);

    gemm128<<<dim3(8, 32), 256, 0, stream>>>(QHb, Wqt, b_q, Qb, nullptr, 4096, 0);
    // fused K+V projection as one wide GEMM (N=2048), A shared via L2 (XCD swizzle)
    gemm128<<<dim3(16, 128), 256, 0, stream>>>(Hb, Wkt, nullptr, Kb, Vtb, 16384, 2);

    attn_flash<<<dim3(4, 16, 8), 512, 0, stream>>>(Qb, Kb, Vtb, mask, Cb, lseP);

    gemm128<<<dim3(8, 32), 256, 0, stream>>>(Cb, Wot, b_o, out, nullptr, 4096, 1);
    attn_amean<<<dim3(32, 8, 8), 256, 0, stream>>>(Qb, Kb, mask, lseP, out + N_QH);
}

// Round 7
// 414.452 us; speedup vs baseline: 1.0775x; 1.0468x over previous
//
#include <hip/hip_runtime.h>
#include <hip/hip_bf16.h>

// ---------------- types ----------------
using short8 = __attribute__((ext_vector_type(8))) short;   // 8 bf16 (4 VGPRs)
using f32x4  = __attribute__((ext_vector_type(4))) float;   // 4 fp32 acc

#define LSK 72   // LDS row stride (shorts) for Ps tile

#define GLDS(gptr, lptr) __builtin_amdgcn_global_load_lds( \
    (const __attribute__((address_space(1))) void*)(gptr), \
    (__attribute__((address_space(3))) void*)(lptr), 16, 0, 0)

static __device__ __forceinline__ short f2b(float f) {
    unsigned u = __builtin_bit_cast(unsigned, f);
    unsigned r = (u + 0x7fffu + ((u >> 16) & 1u)) >> 16;
    return (short)r;
}

// ---------------- convert kernels ----------------
__global__ void cvt_bf16(const float* __restrict__ in, short* __restrict__ out, int n) {
    int i = (blockIdx.x * 256 + threadIdx.x) * 4;
    if (i >= n) return;
    float4 v = *(const float4*)(in + i);
    short4 o = make_short4(f2b(v.x), f2b(v.y), f2b(v.z), f2b(v.w));
    *(short4*)(out + i) = o;
}

// 4 weights f32 [1024][1024] -> Wt bf16 [N][K], dsts contiguous from Wt0
__global__ void cvt_t4(const float* __restrict__ W0, const float* __restrict__ W1,
                       const float* __restrict__ W2, const float* __restrict__ W3,
                       short* __restrict__ Wt0) {
    __shared__ short tile[32][33];
    const float* Ws[4] = {W0, W1, W2, W3};
    const float* W = Ws[blockIdx.z];
    short* Wt = Wt0 + (size_t)blockIdx.z * 1024 * 1024;
    const int K = 1024, N = 1024;
    int n0 = blockIdx.x * 32, k0 = blockIdx.y * 32;
    int tx = threadIdx.x, ty = threadIdx.y; // (32,8)
#pragma unroll
    for (int i = 0; i < 4; i++) {
        int r = ty + i * 8;
        tile[r][tx] = f2b(W[(size_t)(k0 + r) * N + n0 + tx]);
    }
    __syncthreads();
#pragma unroll
    for (int i = 0; i < 4; i++) {
        int r = ty + i * 8;
        Wt[(size_t)(n0 + r) * K + k0 + tx] = tile[tx][r];
    }
}

// ---------------- GEMM: block tile 128m x 64n, BK=64, wave-tile 32x64 ----------------
// mode 0: bf16 [m][n] (N=1024);  mode 1: f32 [m][n] (N=1024)
// mode 2: dual KV (grid.x=32: n<1024 -> Cout=K bf16 [m][1024]; n>=1024 -> Cout2=Vt [b][h][d][s])
// Low-register (32 acc AGPR) + launch_bounds(256,4): 4 blocks/CU for latency hiding.
// XCD swizzle: lin%8 -> XCD m-band, consecutive slots sweep n for A-tile L2 reuse.
__global__ __launch_bounds__(256, 4) void gemm128(
    const short* __restrict__ A, const short* __restrict__ Bt,
    const float* __restrict__ bias, void* __restrict__ Cout, void* __restrict__ Cout2,
    int M, int mode)
{
    __shared__ short As[128 * 64];
    __shared__ short Bs[64 * 64];
    const int tid = threadIdx.x;
    const int w = tid >> 6, L = tid & 63, quad = L >> 4, l16 = L & 15;

    const int lin = blockIdx.y * gridDim.x + blockIdx.x;
    const int xcd = lin & 7, idx = lin >> 3;
    const int mPer = gridDim.y >> 3;
    const int my = xcd * mPer + idx / gridDim.x;
    const int nx = idx % gridDim.x;
    const int n0 = nx * 64, m0 = my * 128;

    const int K = 1024;
    const int mrow0 = w * 32;
    const int srow_in = L >> 3;                        // 0..7 within chunk
    const int sgcol   = ((L & 7) ^ (srow_in & 7)) * 8; // swizzled global col (shorts)

    f32x4 acc[2][4];
#pragma unroll
    for (int mi = 0; mi < 2; mi++)
#pragma unroll
        for (int ni = 0; ni < 4; ni++) acc[mi][ni] = (f32x4){0.f, 0.f, 0.f, 0.f};

    for (int k0 = 0; k0 < K; k0 += 64) {
        // 24 chunks (16 A + 8 B), 6 per wave
#pragma unroll
        for (int j = 0; j < 6; j++) {
            int c = w * 6 + j;
            if (c < 16) {
                int row = c * 8 + srow_in;
                GLDS(A + (size_t)(m0 + row) * K + k0 + sgcol, &As[c * 512]);
            } else {
                int row = (c - 16) * 8 + srow_in;
                GLDS(Bt + (size_t)(n0 + row) * K + k0 + sgcol, &Bs[(c - 16) * 512]);
            }
        }
        __syncthreads();
#pragma unroll
        for (int kk = 0; kk < 64; kk += 32) {
            int swz = (((kk >> 3) + quad) ^ (l16 & 7)) << 3;
            short8 af[2], bf[4];
#pragma unroll
            for (int mi = 0; mi < 2; mi++)
                af[mi] = *(const short8*)&As[(mrow0 + mi * 16 + l16) * 64 + swz];
#pragma unroll
            for (int ni = 0; ni < 4; ni++)
                bf[ni] = *(const short8*)&Bs[(ni * 16 + l16) * 64 + swz];
#pragma unroll
            for (int mi = 0; mi < 2; mi++)
#pragma unroll
                for (int ni = 0; ni < 4; ni++)
                    acc[mi][ni] = __builtin_amdgcn_mfma_f32_16x16x32_bf16(af[mi], bf[ni], acc[mi][ni], 0, 0, 0);
        }
        __syncthreads();
    }
#pragma unroll
    for (int ni = 0; ni < 4; ni++) {
        int n = n0 + ni * 16 + l16;
        float bv = (mode != 2 && bias) ? bias[n] : 0.f;
#pragma unroll
        for (int mi = 0; mi < 2; mi++) {
#pragma unroll
            for (int r = 0; r < 4; r++) {
                int m = m0 + mrow0 + mi * 16 + quad * 4 + r;
                float v = acc[mi][ni][r] + bv;
                if (mode == 1)      ((float*)Cout)[(size_t)m * 1024 + n] = v;
                else if (mode == 0) ((short*)Cout)[(size_t)m * 1024 + n] = f2b(v);
                else {
                    if (n < 1024) ((short*)Cout)[(size_t)m * 1024 + n] = f2b(v);
                    else {
                        int h = (n - 1024) >> 6, d = n & 63;
                        int b = m >> 11, s = m & 2047;
                        ((short*)Cout2)[(((size_t)b * 16 + h) * 64 + d) * 2048 + s] = f2b(v);
                    }
                }
            }
        }
    }
}

// ---------------- flash attention: t-tile=128, s-tile=128, glds swizzled staging ----------------
__global__ __launch_bounds__(512) void attn_flash(
    const short* __restrict__ Qb, const short* __restrict__ Kb, const short* __restrict__ Vtb,
    const int* __restrict__ mask, short* __restrict__ Cb, float* __restrict__ lse)
{
    __shared__ short Qs[128 * 64];
    __shared__ short Ks[128 * 64];      // K rows s0..s0+127
    __shared__ short Vts[128 * 64];     // two [64 d][64 s] halves
    __shared__ short Ps[128 * LSK];
    __shared__ float neg[128];
    const int tid = threadIdx.x;
    const int w = tid >> 6, L = tid & 63, quad = L >> 4, l16 = L & 15;
    const int t0 = blockIdx.x * 128, h = blockIdx.y, b = blockIdx.z;
    const int S = 2048, T = 512, H = 1024;
    const int trow = w * 16;
    const int srow = L >> 3;
    const int sg   = ((L & 7) ^ srow) * 8;

    // stage Q tile [128][64] via glds (2 chunks per wave)
#pragma unroll
    for (int j = 0; j < 2; j++) {
        int row = w * 16 + j * 8 + srow;
        GLDS(Qb + ((size_t)b * T + t0 + row) * H + h * 64 + sg, &Qs[(w * 16 + j * 8) * 64]);
    }
    __syncthreads();
    short8 aq[2];
#pragma unroll
    for (int kk = 0; kk < 2; kk++)
        aq[kk] = *(const short8*)&Qs[(trow + l16) * 64 + ((kk * 4 + quad) ^ (l16 & 7)) * 8];

    f32x4 Oacc[4];
#pragma unroll
    for (int nt = 0; nt < 4; nt++) Oacc[nt] = (f32x4){0.f, 0.f, 0.f, 0.f};
    float lsum[4] = {0.f, 0.f, 0.f, 0.f};

    for (int s0 = 0; s0 < S; s0 += 128) {
        // stage K [128][64] (16 chunks) + Vt 2x[64][64] (16 chunks): 2+2 per wave
#pragma unroll
        for (int j = 0; j < 2; j++) {
            int krow = w * 16 + j * 8 + srow;
            GLDS(Kb + ((size_t)b * S + s0 + krow) * H + h * 64 + sg, &Ks[(w * 16 + j * 8) * 64]);
            int c = w * 2 + j, hf = c >> 3, d0 = (c & 7) * 8;
            GLDS(Vtb + (((size_t)b * 16 + h) * 64 + d0 + srow) * S + s0 + hf * 64 + sg, &Vts[c * 512]);
        }
        if (tid < 128) neg[tid] = mask[(size_t)b * S + s0 + tid] ? 0.f : -1e20f;
        __syncthreads();
#pragma unroll
        for (int hf = 0; hf < 2; hf++) {
            // S = Q K^T for this 64-s half
            f32x4 sacc[4];
#pragma unroll
            for (int nt = 0; nt < 4; nt++) sacc[nt] = (f32x4){0.f, 0.f, 0.f, 0.f};
#pragma unroll
            for (int kk = 0; kk < 2; kk++) {
#pragma unroll
                for (int nt = 0; nt < 4; nt++) {
                    short8 bf = *(const short8*)&Ks[(hf * 64 + nt * 16 + l16) * 64 + ((kk * 4 + quad) ^ (l16 & 7)) * 8];
                    sacc[nt] = __builtin_amdgcn_mfma_f32_16x16x32_bf16(aq[kk], bf, sacc[nt], 0, 0, 0);
                }
            }
            // p = exp(s/8 + neg); write Ps (wave-private rows)
#pragma unroll
            for (int nt = 0; nt < 4; nt++) {
                float ng = neg[hf * 64 + nt * 16 + l16];
#pragma unroll
                for (int r = 0; r < 4; r++) {
                    float e = __expf(fmaf(sacc[nt][r], 0.125f, ng));
                    lsum[r] += e;
                    Ps[(trow + quad * 4 + r) * LSK + nt * 16 + l16] = f2b(e);
                }
            }
            // O += P V
#pragma unroll
            for (int kk = 0; kk < 2; kk++) {
                short8 af = *(const short8*)&Ps[(trow + l16) * LSK + kk * 32 + quad * 8];
#pragma unroll
                for (int nt = 0; nt < 4; nt++) {
                    short8 bf = *(const short8*)&Vts[hf * 4096 + (nt * 16 + l16) * 64 + ((kk * 4 + quad) ^ (l16 & 7)) * 8];
                    Oacc[nt] = __builtin_amdgcn_mfma_f32_16x16x32_bf16(af, bf, Oacc[nt], 0, 0, 0);
                }
            }
        }
        __syncthreads();
    }
    // rowsum reduce across the 16 lanes of each quad-group
#pragma unroll
    for (int r = 0; r < 4; r++) {
#pragma unroll
        for (int off = 1; off < 16; off <<= 1)
            lsum[r] += __shfl_xor(lsum[r], off, 64);
    }
#pragma unroll
    for (int r = 0; r < 4; r++) {
        float inv = 1.0f / lsum[r];
        int t = t0 + trow + quad * 4 + r;
#pragma unroll
        for (int nt = 0; nt < 4; nt++) {
            int d = nt * 16 + l16;
            Cb[((size_t)b * T + t) * H + h * 64 + d] = f2b(Oacc[nt][r] * inv);
        }
        if (l16 == 0)
            lse[((size_t)b * 16 + h) * T + t] = __logf(lsum[r]);
    }
}

// ---------------- a_mean: out[b][t][s] = mean_h exp(qk/8 + neg - lse_h) ----------------
__global__ __launch_bounds__(256) void attn_amean(
    const short* __restrict__ Qb, const short* __restrict__ Kb,
    const int* __restrict__ mask, const float* __restrict__ lse, float* __restrict__ outA)
{
    __shared__ short Qs[64 * 64];
    __shared__ short Ks[64 * 64];
    __shared__ float neg[64];
    __shared__ float lss[16 * 64];
    const int tid = threadIdx.x;
    const int w = tid >> 6, L = tid & 63, quad = L >> 4, l16 = L & 15;
    const int s0 = blockIdx.x * 64, t0 = blockIdx.y * 64, b = blockIdx.z;
    const int S = 2048, T = 512, H = 1024;
    const int srow = L >> 3;
    const int sg   = ((L & 7) ^ srow) * 8;

    if (tid < 64) neg[tid] = mask[(size_t)b * S + s0 + tid] ? 0.f : -1e20f;
    for (int i = tid; i < 16 * 64; i += 256) {
        int hh = i >> 6, tt = i & 63;
        lss[i] = lse[((size_t)b * 16 + hh) * T + t0 + tt];
    }
    float am[4][4] = {};
    for (int h = 0; h < 16; h++) {
        __syncthreads();  // protects neg/lss on first iter, prior-head reads after
#pragma unroll
        for (int j = 0; j < 2; j++) {
            int row = w * 16 + j * 8 + srow;
            GLDS(Qb + ((size_t)b * T + t0 + row) * H + h * 64 + sg, &Qs[(w * 16 + j * 8) * 64]);
            GLDS(Kb + ((size_t)b * S + s0 + row) * H + h * 64 + sg, &Ks[(w * 16 + j * 8) * 64]);
        }
        __syncthreads();
        short8 aq[2];
#pragma unroll
        for (int kk = 0; kk < 2; kk++)
            aq[kk] = *(const short8*)&Qs[(w * 16 + l16) * 64 + ((kk * 4 + quad) ^ (l16 & 7)) * 8];
        f32x4 sacc[4];
#pragma unroll
        for (int nt = 0; nt < 4; nt++) sacc[nt] = (f32x4){0.f, 0.f, 0.f, 0.f};
#pragma unroll
        for (int kk = 0; kk < 2; kk++) {
#pragma unroll
            for (int nt = 0; nt < 4; nt++) {
                short8 bf = *(const short8*)&Ks[(nt * 16 + l16) * 64 + ((kk * 4 + quad) ^ (l16 & 7)) * 8];
                sacc[nt] = __builtin_amdgcn_mfma_f32_16x16x32_bf16(aq[kk], bf, sacc[nt], 0, 0, 0);
            }
        }
#pragma unroll
        for (int nt = 0; nt < 4; nt++) {
            float ng = neg[nt * 16 + l16];
#pragma unroll
            for (int r = 0; r < 4; r++) {
                int trow = w * 16 + quad * 4 + r;
                am[nt][r] += __expf(fmaf(sacc[nt][r], 0.125f, ng - lss[h * 64 + trow]));
            }
        }
    }
#pragma unroll
    for (int r = 0; r < 4; r++) {
        int t = t0 + w * 16 + quad * 4 + r;
#pragma unroll
        for (int nt = 0; nt < 4; nt++) {
            int s = s0 + nt * 16 + l16;
            outA[((size_t)b * T + t) * S + s] = am[nt][r] * 0.0625f;
        }
    }
}

// ---------------- launch ----------------
extern "C" void kernel_launch(void* const* d_in, const int* in_sizes, int n_in,
                              void* d_out, int out_size, void* d_ws, size_t ws_size,
                              hipStream_t stream) {
    const float* hiddens = (const float*)d_in[0];
    const float* query   = (const float*)d_in[1];
    const int*   mask    = (const int*)d_in[2];
    const float* W_q = (const float*)d_in[3];
    const float* b_q = (const float*)d_in[4];
    const float* W_k = (const float*)d_in[5];
    const float* W_v = (const float*)d_in[6];
    const float* W_o = (const float*)d_in[7];
    const float* b_o = (const float*)d_in[8];
    float* out = (float*)d_out;

    constexpr size_t N_H  = 8UL * 2048 * 1024;  // 16777216
    constexpr size_t N_QH = 8UL * 512 * 1024;   // 4194304
    constexpr size_t N_W  = 1024UL * 1024;      // 1048576
    char* ws = (char*)d_ws;
    short* Hb   = (short*)(ws);
    short* QHb  = (short*)(ws + N_H * 2);
    short* Wqt  = (short*)(ws + N_H * 2 + N_QH * 2);
    short* Wkt  = Wqt + N_W;
    short* Wvt  = Wkt + N_W;   // contiguous after Wkt: enables N=2048 dual GEMM
    short* Wot  = Wvt + N_W;
    short* Qb   = Wot + N_W;
    short* Kb   = Qb + N_QH;
    short* Vtb  = Kb + N_H;    // V stored transposed: [b][h][d][s]
    short* Cb   = Vtb + N_H;
    float* lseP = (float*)(Cb + N_QH);

    cvt_bf16<<<16384, 256, 0, stream>>>(hiddens, Hb, (int)N_H);
    cvt_bf16<<<4096, 256, 0, stream>>>(query, QHb, (int)N_QH);
    cvt_t4<<<dim3(32, 32, 4), dim3(32, 8), 0, stream>>>(W_q, W_k, W_v, W_o, Wqt);

    gemm128<<<dim3(16, 32), 256, 0, stream>>>(QHb, Wqt, b_q, Qb, nullptr, 4096, 0);
    // fused K+V projection as one wide GEMM (N=2048), A shared via L2 (XCD swizzle)
    gemm128<<<dim3(32, 128), 256, 0, stream>>>(Hb, Wkt, nullptr, Kb, Vtb, 16384, 2);

    attn_flash<<<dim3(4, 16, 8), 512, 0, stream>>>(Qb, Kb, Vtb, mask, Cb, lseP);

    gemm128<<<dim3(16, 32), 256, 0, stream>>>(Cb, Wot, b_o, out, nullptr, 4096, 1);
    attn_amean<<<dim3(32, 8, 8), 256, 0, stream>>>(Qb, Kb, mask, lseP, out + N_QH);
}